// Round 12
// baseline (658.533 us; speedup 1.0000x reference)
//
#include <hip/hip_runtime.h>

typedef unsigned short bf16_t;
typedef __attribute__((ext_vector_type(8))) short bf16x8;
typedef __attribute__((ext_vector_type(4))) float f32x4;

// ---------------- conversions ----------------
__device__ __forceinline__ float bf2f(bf16_t u) {
  union { unsigned int i; float f; } v; v.i = ((unsigned int)u) << 16; return v.f;
}
__device__ __forceinline__ bf16_t f2bf(float f) {
  union { float f; unsigned int i; } v; v.f = f;
  unsigned int u = v.i;
  u += 0x7fffu + ((u >> 16) & 1u);   // RNE
  return (bf16_t)(u >> 16);
}
__device__ __forceinline__ float gelu_exact(float x) {
  return 0.5f * x * (1.0f + erff(x * 0.7071067811865475f));
}
// async global->LDS 16B copy: per-wave, lane l's 16B lands at lds_base + l*16
__device__ __forceinline__ void g2l16(bf16_t* l, const bf16_t* g) {
  __builtin_amdgcn_global_load_lds(
      (const __attribute__((address_space(1))) unsigned int*)g,
      (__attribute__((address_space(3))) unsigned int*)l, 16, 0, 0);
}

// ---------------- fp32 -> bf16 convert ----------------
__global__ __launch_bounds__(256) void f2bf_kernel(const float4* __restrict__ s,
                                                   ushort4* __restrict__ d, int n4) {
  int i = blockIdx.x * 256 + threadIdx.x;
  if (i < n4) {
    float4 f = s[i];
    ushort4 u; u.x = f2bf(f.x); u.y = f2bf(f.y); u.z = f2bf(f.z); u.w = f2bf(f.w);
    d[i] = u;
  }
}

// ---------------- LayerNorm: one wave per row of 512, fp32 in -> bf16 out ----------------
__global__ __launch_bounds__(256) void ln_kernel(const float* __restrict__ x,
                                                 const float* __restrict__ g,
                                                 const float* __restrict__ bta,
                                                 bf16_t* __restrict__ y) {
  const int w = threadIdx.x >> 6, lane = threadIdx.x & 63;
  const long row = (long)blockIdx.x * 4 + w;
  const long base = row * 512;
  const int c0 = lane << 2;
  float v[8];
  float4 f0 = *(const float4*)(x + base + c0);
  float4 f1 = *(const float4*)(x + base + 256 + c0);
  v[0]=f0.x; v[1]=f0.y; v[2]=f0.z; v[3]=f0.w;
  v[4]=f1.x; v[5]=f1.y; v[6]=f1.z; v[7]=f1.w;
  float s = 0.f;
#pragma unroll
  for (int c=0;c<8;++c) s += v[c];
#pragma unroll
  for (int o=32;o>0;o>>=1) s += __shfl_xor(s, o);
  const float mean = s * 0.001953125f;
  float ss = 0.f;
#pragma unroll
  for (int c=0;c<8;++c) { float d = v[c]-mean; ss += d*d; }
#pragma unroll
  for (int o=32;o>0;o>>=1) ss += __shfl_xor(ss, o);
  const float rstd = rsqrtf(ss * 0.001953125f + 1e-5f);
  ushort4 o0, o1;
  o0.x = f2bf((v[0]-mean)*rstd*g[c0+0] + bta[c0+0]);
  o0.y = f2bf((v[1]-mean)*rstd*g[c0+1] + bta[c0+1]);
  o0.z = f2bf((v[2]-mean)*rstd*g[c0+2] + bta[c0+2]);
  o0.w = f2bf((v[3]-mean)*rstd*g[c0+3] + bta[c0+3]);
  o1.x = f2bf((v[4]-mean)*rstd*g[256+c0+0] + bta[256+c0+0]);
  o1.y = f2bf((v[5]-mean)*rstd*g[256+c0+1] + bta[256+c0+1]);
  o1.z = f2bf((v[6]-mean)*rstd*g[256+c0+2] + bta[256+c0+2]);
  o1.w = f2bf((v[7]-mean)*rstd*g[256+c0+3] + bta[256+c0+3]);
  *(ushort4*)(y + base + c0) = o0;
  *(ushort4*)(y + base + 256 + c0) = o1;
}

// ---------------- MFMA GEMM  C = A @ W^T  (bf16 in, +bias/gelu/scale/+res fp32) ------------
// MT=128: m97 structure — global_load_lds staging A[128][32]+W[128][32], 2 barriers/K-step.
// MT=64 : direct global->reg fragment loads, 2-deep prefetch (each load covered by
//         two 16-MFMA phases; addresses clamped so all loads are unconditional).
// XCD-aware block swizzle: the n-blocks sharing an A panel land on one XCD's L2.
struct MmaNT {
  const bf16_t* A; const bf16_t* W; const float* bias; const float* res; void* C;
  long lda, sAb, sAh;
  long ldw, sWb, sWh;
  long ldr, sRb, sRh;
  long ldc, sCb, sCh;
  int K, zdiv, cBf, act;
  float scale;
};

template <int MT>
__global__ __launch_bounds__(256) void mma_nt_kernel(MmaNT p) {
  constexpr int FM = MT / 32;          // m-frags per wave (wave covers MT/2 rows)
  constexpr int TILE_E = (MT + 128) * 32;     // A+W staging tiles (bf16 elems)
  constexpr int ST_E = MT * 128;              // epilogue staging
  constexpr int SM_E = (TILE_E > ST_E) ? TILE_E : ST_E;
  __shared__ __align__(16) bf16_t smem[SM_E];
  bf16_t* Al = smem;
  bf16_t* Wl = smem + MT * 32;
  const int tid = threadIdx.x;
  const int wid = tid >> 6, lane = tid & 63;
  const int wm = wid & 1, wn = wid >> 1;     // waves 2x2 over (M/2, 128/2)
  const int quad = lane >> 4, l16 = lane & 15;
  const int z = blockIdx.z;
  const int zb = z / p.zdiv, zh = z % p.zdiv;

  // bijective XCD swizzle (all grids are multiples of 8 workgroups, z==1 for GEMMs)
  const int nbx = gridDim.x;
  const int nwg = nbx * gridDim.y;
  const int flat = blockIdx.y * nbx + blockIdx.x;
  const int sw = (flat & 7) * (nwg >> 3) + (flat >> 3);
  const int bx = sw % nbx, by = sw / nbx;

  const long m0 = (long)by * MT;
  const long n0 = (long)bx * 128;

  f32x4 zero4 = {0.f, 0.f, 0.f, 0.f};
  f32x4 acc[FM][4];
#pragma unroll
  for (int fm = 0; fm < FM; ++fm)
#pragma unroll
    for (int fn = 0; fn < 4; ++fn) acc[fm][fn] = zero4;

  if constexpr (MT == 128) {
    // ---- async-DMA staged K-loop (m97 structure) ----
    const bf16_t* Ag = p.A + (long)zb * p.sAb + (long)zh * p.sAh + m0 * p.lda;
    const bf16_t* Wg = p.W + (long)zb * p.sWb + (long)zh * p.sWh + n0 * p.ldw;
    const int sr = lane >> 2;           // lane's row within a 16-row wave group
    const int sc = (lane & 3) * 8;      // lane's col group (8 bf16 = 16B)
    for (int kc = 0; kc < p.K; kc += 32) {
      // stage A tile [128][32]: 2 calls x (4 waves x 16 rows)
#pragma unroll
      for (int j = 0; j < 2; ++j)
        g2l16(&Al[(j * 64 + wid * 16) * 32],
              Ag + (long)(j * 64 + wid * 16 + sr) * p.lda + kc + sc);
      // stage W tile [128][32]
#pragma unroll
      for (int j = 0; j < 2; ++j)
        g2l16(&Wl[(j * 64 + wid * 16) * 32],
              Wg + (long)(j * 64 + wid * 16 + sr) * p.ldw + kc + sc);
      __syncthreads();   // drains DMA (vmcnt) + sync
      bf16x8 af[FM], wf[4];
#pragma unroll
      for (int fm = 0; fm < FM; ++fm)
        af[fm] = *(const bf16x8*)&Al[(wm * 64 + fm * 16 + l16) * 32 + quad * 8];
#pragma unroll
      for (int fn = 0; fn < 4; ++fn)
        wf[fn] = *(const bf16x8*)&Wl[(wn * 64 + fn * 16 + l16) * 32 + quad * 8];
#pragma unroll
      for (int fm = 0; fm < FM; ++fm)
#pragma unroll
        for (int fn = 0; fn < 4; ++fn)
          acc[fm][fn] = __builtin_amdgcn_mfma_f32_16x16x32_bf16(af[fm], wf[fn], acc[fm][fn], 0, 0, 0);
      __syncthreads();   // all reads done before next stage overwrites
    }
  } else {
    // ---- direct-to-reg K-loop, 2-deep prefetch (K is a multiple of 64) ----
    const bf16_t* Ag = p.A + (long)zb * p.sAb + (long)zh * p.sAh +
                       (m0 + wm * (MT / 2) + l16) * p.lda;
    const bf16_t* Wg = p.W + (long)zb * p.sWb + (long)zh * p.sWh +
                       (n0 + wn * 64 + l16) * p.ldw;
    bf16x8 a0[FM], w0[4], a1[FM], w1[4], an0[FM], wn0[4], an1[FM], wn1[4];
#pragma unroll
    for (int fm = 0; fm < FM; ++fm) {
      a0[fm] = *(const bf16x8*)(Ag + (long)(fm * 16) * p.lda + quad * 8);
      a1[fm] = *(const bf16x8*)(Ag + (long)(fm * 16) * p.lda + 32 + quad * 8);
    }
#pragma unroll
    for (int fn = 0; fn < 4; ++fn) {
      w0[fn] = *(const bf16x8*)(Wg + (long)(fn * 16) * p.ldw + quad * 8);
      w1[fn] = *(const bf16x8*)(Wg + (long)(fn * 16) * p.ldw + 32 + quad * 8);
    }
    for (int kc = 0; kc < p.K; kc += 64) {
      int k2 = kc + 64;
      if (k2 > p.K - 64) k2 = p.K - 64;   // clamp: last-iter loads redundant but safe
      // issue loads for step kc+64 (covered by the two MFMA phases below)
#pragma unroll
      for (int fm = 0; fm < FM; ++fm)
        an0[fm] = *(const bf16x8*)(Ag + (long)(fm * 16) * p.lda + k2 + quad * 8);
#pragma unroll
      for (int fn = 0; fn < 4; ++fn)
        wn0[fn] = *(const bf16x8*)(Wg + (long)(fn * 16) * p.ldw + k2 + quad * 8);
#pragma unroll
      for (int fm = 0; fm < FM; ++fm)
#pragma unroll
        for (int fn = 0; fn < 4; ++fn)
          acc[fm][fn] = __builtin_amdgcn_mfma_f32_16x16x32_bf16(a0[fm], w0[fn], acc[fm][fn], 0, 0, 0);
      // issue loads for step kc+96
#pragma unroll
      for (int fm = 0; fm < FM; ++fm)
        an1[fm] = *(const bf16x8*)(Ag + (long)(fm * 16) * p.lda + k2 + 32 + quad * 8);
#pragma unroll
      for (int fn = 0; fn < 4; ++fn)
        wn1[fn] = *(const bf16x8*)(Wg + (long)(fn * 16) * p.ldw + k2 + 32 + quad * 8);
#pragma unroll
      for (int fm = 0; fm < FM; ++fm)
#pragma unroll
        for (int fn = 0; fn < 4; ++fn)
          acc[fm][fn] = __builtin_amdgcn_mfma_f32_16x16x32_bf16(a1[fm], w1[fn], acc[fm][fn], 0, 0, 0);
#pragma unroll
      for (int fm = 0; fm < FM; ++fm) { a0[fm] = an0[fm]; a1[fm] = an1[fm]; }
#pragma unroll
      for (int fn = 0; fn < 4; ++fn) { w0[fn] = wn0[fn]; w1[fn] = wn1[fn]; }
    }
  }

  const long cOff = (long)zb * p.sCb + (long)zh * p.sCh;
  const long rOff = (long)zb * p.sRb + (long)zh * p.sRh;
  if (p.cBf) {
    // ---- staged epilogue: postprocess -> LDS [MT][128] -> coalesced uint4 stores ----
#pragma unroll
    for (int fm = 0; fm < FM; ++fm) {
#pragma unroll
      for (int fn = 0; fn < 4; ++fn) {
        const int lc = wn * 64 + fn * 16 + l16;
        const long col = n0 + lc;
        const float bv = p.bias ? p.bias[col] : 0.f;
#pragma unroll
        for (int r = 0; r < 4; ++r) {
          const int lr = wm * (MT / 2) + fm * 16 + quad * 4 + r;
          float t = acc[fm][fn][r] + bv;
          if (p.act) t = gelu_exact(t);
          t *= p.scale;
          if (p.res) t += p.res[rOff + (m0 + lr) * p.ldr + col];
          smem[lr * 128 + lc] = f2bf(t);
        }
      }
    }
    __syncthreads();
    bf16_t* Cg = (bf16_t*)p.C + cOff + m0 * p.ldc + n0;
#pragma unroll
    for (int i = 0; i < MT / 16; ++i) {     // MT rows x 16 chunks(16B)/row
      const int flat2 = tid + i * 256;
      const int r = flat2 >> 4, c = (flat2 & 15) * 8;
      *(uint4*)(Cg + (long)r * p.ldc + c) = *(const uint4*)&smem[r * 128 + c];
    }
  } else {
    // fp32 output path (MT=64 launches only) — direct stores
#pragma unroll
    for (int fm = 0; fm < FM; ++fm) {
#pragma unroll
      for (int fn = 0; fn < 4; ++fn) {
        const long col = n0 + wn * 64 + fn * 16 + l16;
        const float bv = p.bias ? p.bias[col] : 0.f;
#pragma unroll
        for (int r = 0; r < 4; ++r) {
          const long row = m0 + wm * (MT / 2) + fm * 16 + quad * 4 + r;
          float t = acc[fm][fn][r] + bv;
          if (p.act) t = gelu_exact(t);
          t *= p.scale;
          if (p.res) t += p.res[rOff + row * p.ldr + col];
          ((float*)p.C)[cOff + row * p.ldc + col] = t;
        }
      }
    }
  }
}

// ---------------- tile transpose: per z, [N][D] slice (ld) -> [D][N] dst ----------------
struct TransP {
  const bf16_t* src; bf16_t* dst;
  long sSb, sSh, ld;
  int nh, N, D;
};

__global__ __launch_bounds__(256) void transpose_kernel(TransP p) {
  __shared__ bf16_t T[64][72];
  const int tid = threadIdx.x;
  const int z = blockIdx.z;
  const int zb = z / p.nh, zh = z % p.nh;
  const long n0 = (long)blockIdx.x * 64;
  const long d0 = (long)blockIdx.y * 64;
  const bf16_t* src = p.src + (long)zb * p.sSb + (long)zh * p.sSh;
  bf16_t* dst = p.dst + (long)z * p.D * p.N;
#pragma unroll
  for (int i = 0; i < 2; ++i) {
    int flat = tid + i * 256, r = flat >> 3, cg = flat & 7;
    uint4 v = *(const uint4*)(src + (n0 + r) * p.ld + d0 + cg * 8);
    *(uint4*)&T[r][cg * 8] = v;
  }
  __syncthreads();
#pragma unroll
  for (int i = 0; i < 2; ++i) {
    int flat = tid + i * 256, dr = flat >> 3, ncg = flat & 7;
    uint4 o;
    unsigned int* op = (unsigned int*)&o;
#pragma unroll
    for (int j = 0; j < 4; ++j)
      op[j] = (unsigned int)T[ncg * 8 + 2 * j][dr] | ((unsigned int)T[ncg * 8 + 2 * j + 1][dr] << 16);
    *(uint4*)(dst + (d0 + dr) * p.N + n0 + ncg * 8) = o;
  }
}

// ---------------- split-KV flash attention, DMA-staged, 8-wave blocks (pass 1) -------------
// Block: 128 q-rows (8 waves x 16), one (b,h), one N-segment; k-tile = 64 N-rows.
// K/VT staged via global_load_lds into LINEAR tiles with both-sides XOR swizzle.
// Prior double-buffered (pr0/pr1); defer-max (THR=8) skips the O/l rescale.
// T5: s_setprio(1) around the MFMA clusters (8-wave phase-split gives the CU
// scheduler role diversity to arbitrate).
struct FlashP2 {
  const bf16_t* Q; const bf16_t* K; const bf16_t* VT; const float* prior;
  float* partO; float* partML;
  long ldq, sQb, sQh;
  long ldk, sKb, sKh;
  long sVz, sPb;
  int nh, N, segN;
  float scale;
};

template <int DH, int HASP>
__global__ __launch_bounds__(512) void flash3_kernel(FlashP2 p) {
  constexpr int KK = DH / 32;       // k-frags over dh (QK^T)
  constexpr int NFO = DH / 16;      // output col frags
  constexpr int KE = 64 * DH;       // Kl elems (linear [64][DH])
  constexpr int VE = DH * 64;       // Vl elems (linear [DH][64])
  constexpr int PE = 128 * 72;      // Pl elems [128 q-rows][72]
  __shared__ __align__(16) bf16_t smem[KE + VE + PE];
  bf16_t* Kl = smem;
  bf16_t* Vl = smem + KE;
  bf16_t* Pl = smem + KE + VE;
  const int tid = threadIdx.x;
  const int w = tid >> 6, lane = tid & 63;      // 8 waves
  const int quad = lane >> 4, l16 = lane & 15;
  const int z = blockIdx.z;
  const int zb = z / p.nh, zh = z % p.nh;
  const int qr0 = blockIdx.y * 128 + w * 16;    // wave's first q-row
  const bf16_t* Q = p.Q + (long)zb * p.sQb + (long)zh * p.sQh + (long)qr0 * p.ldq;
  const bf16_t* K = p.K + (long)zb * p.sKb + (long)zh * p.sKh;
  const bf16_t* VT = p.VT + (long)z * p.sVz;

  // persistent Q A-frags (16 q-rows per wave)
  bf16x8 qf[KK];
#pragma unroll
  for (int kk = 0; kk < KK; ++kk)
    qf[kk] = *(const bf16x8*)(Q + (long)l16 * p.ldq + kk * 32 + quad * 8);

  f32x4 zero4 = {0.f, 0.f, 0.f, 0.f};
  f32x4 O[NFO];
  float m_[4], l_[4];
#pragma unroll
  for (int f = 0; f < NFO; ++f) O[f] = zero4;
#pragma unroll
  for (int r = 0; r < 4; ++r) { m_[r] = -1e30f; l_[r] = 0.f; }

  // staging geometry (8 waves)
  constexpr int LPR = DH / 8;       // lanes per K row
  constexpr int RPC = 512 / DH;     // K rows per 1024B DMA call
  constexpr int KCW = (64 / RPC) / 8;    // K calls per wave (DH=128:2, DH=64:1)
  constexpr int VCW = (DH / 8) / 8;      // V calls per wave (DH=128:2, DH=64:1)
  const int krl = lane / LPR;            // K: lane's row within a call group
  const int kcb = (lane % LPR) * 16;     // K: lane's byte col
  const int vrl = lane >> 3;             // V: 8 lanes per 128B row
  const int vcb = (lane & 7) * 16;

  const float* PRrow = HASP ? (p.prior + (long)zb * p.sPb +
                               (long)(qr0 + quad * 4) * p.N) : (const float*)nullptr;

  const int k0 = blockIdx.x * p.segN;
  const int kend = k0 + p.segN;     // segN/64 is even for all launches

  float pr0[4][4], pr1[4][4];
  if (HASP) {
#pragma unroll
    for (int nf = 0; nf < 4; ++nf)
#pragma unroll
      for (int r = 0; r < 4; ++r)
        pr0[nf][r] = PRrow[(long)r * p.N + k0 + nf * 16 + l16];
  }

  auto body = [&](int ktc, float (&prC)[4][4], float (&prN)[4][4]) {
    __syncthreads();   // prior iteration's Kl/Vl reads complete
    // ---- stage K tile [64][DH] via DMA, source pre-swizzled ----
#pragma unroll
    for (int j = 0; j < KCW; ++j) {
      const int R0 = (w + 8 * j) * RPC;
      const int r = R0 + krl;
      const int cs = kcb ^ ((r & 7) << 4);
      g2l16(&Kl[R0 * DH], K + (long)(ktc + r) * p.ldk + (cs >> 1));
    }
    // ---- stage VT tile [DH][64] via DMA, source pre-swizzled ----
#pragma unroll
    for (int j = 0; j < VCW; ++j) {
      const int R0 = (w + 8 * j) * 8;
      const int r = R0 + vrl;
      const int cs = vcb ^ ((r & 7) << 4);
      g2l16(&Vl[R0 * 64], VT + (long)r * p.N + ktc + (cs >> 1));
    }
    __syncthreads();   // vmcnt(0) drain: tiles ready (+ prN loads from prev iter)
    // ---- prefetch NEXT tile's prior; lands under this tile's compute ----
    if (HASP) {
      int kn = ktc + 64;
      if (kn > p.N - 64) kn = p.N - 64;   // clamp (last tile: values unused)
#pragma unroll
      for (int nf = 0; nf < 4; ++nf)
#pragma unroll
        for (int r = 0; r < 4; ++r)
          prN[nf][r] = PRrow[(long)r * p.N + kn + nf * 16 + l16];
    }
    // ---- S = Q K^T (kf from swizzled Kl) ----
    f32x4 s[4];
#pragma unroll
    for (int nf = 0; nf < 4; ++nf) s[nf] = zero4;
    __builtin_amdgcn_s_setprio(1);
#pragma unroll
    for (int nf = 0; nf < 4; ++nf)
#pragma unroll
      for (int kk = 0; kk < KK; ++kk) {
        bf16x8 kf = *(const bf16x8*)&Kl[(nf * 16 + l16) * DH +
                                        ((kk * 32 + quad * 8) ^ ((l16 & 7) << 3))];
        s[nf] = __builtin_amdgcn_mfma_f32_16x16x32_bf16(qf[kk], kf, s[nf], 0, 0, 0);
      }
    __builtin_amdgcn_s_setprio(0);
    // ---- scale + prior, tile row-max ----
    float tm[4];
#pragma unroll
    for (int r = 0; r < 4; ++r) tm[r] = -1e30f;
#pragma unroll
    for (int nf = 0; nf < 4; ++nf)
#pragma unroll
      for (int r = 0; r < 4; ++r) {
        float t = s[nf][r] * p.scale;
        if (HASP) t += prC[nf][r];
        s[nf][r] = t;
        tm[r] = fmaxf(tm[r], t);
      }
#pragma unroll
    for (int off = 1; off < 16; off <<= 1)
#pragma unroll
      for (int r = 0; r < 4; ++r) tm[r] = fmaxf(tm[r], __shfl_xor(tm[r], off));
    // ---- online softmax, defer-max (skip rescale when max doesn't grow) ----
    const int ok = (tm[0] <= m_[0] + 8.f) && (tm[1] <= m_[1] + 8.f) &&
                   (tm[2] <= m_[2] + 8.f) && (tm[3] <= m_[3] + 8.f);
    if (!__all(ok)) {
      float alpha[4];
#pragma unroll
      for (int r = 0; r < 4; ++r) {
        float mn = fmaxf(m_[r], tm[r]);
        alpha[r] = __expf(m_[r] - mn);
        m_[r] = mn;
        l_[r] *= alpha[r];
      }
#pragma unroll
      for (int f = 0; f < NFO; ++f)
#pragma unroll
        for (int r = 0; r < 4; ++r) O[f][r] *= alpha[r];
    }
    float rs[4];
#pragma unroll
    for (int r = 0; r < 4; ++r) rs[r] = 0.f;
#pragma unroll
    for (int nf = 0; nf < 4; ++nf)
#pragma unroll
      for (int r = 0; r < 4; ++r) {
        float pv = __expf(s[nf][r] - m_[r]);   // bounded by e^8 under defer
        s[nf][r] = pv;
        rs[r] += pv;
      }
#pragma unroll
    for (int off = 1; off < 16; off <<= 1)
#pragma unroll
      for (int r = 0; r < 4; ++r) rs[r] += __shfl_xor(rs[r], off);
#pragma unroll
    for (int r = 0; r < 4; ++r) l_[r] += rs[r];
    // ---- P: C-layout -> LDS (wave-private rows) -> A-layout ----
#pragma unroll
    for (int nf = 0; nf < 4; ++nf)
#pragma unroll
      for (int r = 0; r < 4; ++r)
        Pl[(w * 16 + quad * 4 + r) * 72 + nf * 16 + l16] = f2bf(s[nf][r]);
    bf16x8 pf[2];
#pragma unroll
    for (int kk2 = 0; kk2 < 2; ++kk2)
      pf[kk2] = *(const bf16x8*)&Pl[(w * 16 + l16) * 72 + kk2 * 32 + quad * 8];
    __builtin_amdgcn_s_setprio(1);
#pragma unroll
    for (int f = 0; f < NFO; ++f)
#pragma unroll
      for (int kk2 = 0; kk2 < 2; ++kk2) {
        bf16x8 vf = *(const bf16x8*)&Vl[(f * 16 + l16) * 64 +
                                        ((kk2 * 32 + quad * 8) ^ ((l16 & 7) << 3))];
        O[f] = __builtin_amdgcn_mfma_f32_16x16x32_bf16(pf[kk2], vf, O[f], 0, 0, 0);
      }
    __builtin_amdgcn_s_setprio(0);
  };

  for (int kt = k0; kt < kend; kt += 128) {
    body(kt, pr0, pr1);
    body(kt + 64, pr1, pr0);
  }

  // ---- write partials (128 q-rows per tile) ----
  const long t = ((long)z * gridDim.y + blockIdx.y) * gridDim.x + blockIdx.x;
  float* PO = p.partO + t * (128 * DH);
  float* PM = p.partML + t * 256;
  const int row = w * 16 + quad * 4;
#pragma unroll
  for (int f = 0; f < NFO; ++f)
#pragma unroll
    for (int r = 0; r < 4; ++r)
      PO[(long)(row + r) * DH + f * 16 + l16] = O[f][r];
  if (l16 == 0) {
#pragma unroll
    for (int r = 0; r < 4; ++r) {
      PM[(row + r) * 2 + 0] = m_[r];
      PM[(row + r) * 2 + 1] = l_[r];
    }
  }
}

// ---------------- flash pass 2: merge NS segment partials, normalize, store bf16 ----------
// 128-row tiles; 256 threads = 128 rows x 2 col-halves.
struct MergeP {
  const float* partO; const float* partML; bf16_t* C;
  long ldc, sCb;
  int nh, y;
};

template <int DH, int NS>
__global__ __launch_bounds__(256) void fmerge_kernel(MergeP p) {
  const int tid = threadIdx.x;
  const int r = tid >> 1, ch = tid & 1;          // 128 rows x 2 col-halves
  const int blk = blockIdx.x;
  const int z = blk / p.y, qb = blk % p.y;
  const int zb = z / p.nh, zh = z % p.nh;
  const long t0 = (long)blk * NS;
  float mm[NS], wgt[NS];
  float mstar = -1e30f;
#pragma unroll
  for (int s = 0; s < NS; ++s) {
    mm[s] = p.partML[(t0 + s) * 256 + r * 2];
    mstar = fmaxf(mstar, mm[s]);
  }
  float lsum = 0.f;
#pragma unroll
  for (int s = 0; s < NS; ++s) {
    wgt[s] = __expf(mm[s] - mstar);
    lsum += wgt[s] * p.partML[(t0 + s) * 256 + r * 2 + 1];
  }
  const float inv = 1.0f / lsum;
  const int c0 = ch * (DH / 2);
  bf16_t* Cp = p.C + (long)zb * p.sCb + (long)(qb * 128 + r) * p.ldc + (long)zh * DH + c0;
#pragma unroll
  for (int c = 0; c < DH / 2; c += 4) {
    float4 acc = make_float4(0.f, 0.f, 0.f, 0.f);
#pragma unroll
    for (int s = 0; s < NS; ++s) {
      float4 v = *(const float4*)(p.partO + (t0 + s) * (128 * DH) + (long)r * DH + c0 + c);
      acc.x += wgt[s] * v.x; acc.y += wgt[s] * v.y;
      acc.z += wgt[s] * v.z; acc.w += wgt[s] * v.w;
    }
    ushort4 o;
    o.x = f2bf(acc.x * inv); o.y = f2bf(acc.y * inv);
    o.z = f2bf(acc.z * inv); o.w = f2bf(acc.w * inv);
    *(ushort4*)(Cp + c) = o;
  }
}

// ---------------- host ----------------
#define MB(x) ((long)(x) << 20)

extern "C" void kernel_launch(void* const* d_in, const int* in_sizes, int n_in,
                              void* d_out, int out_size, void* d_ws, size_t ws_size,
                              hipStream_t stream) {
  const float* motion      = (const float*)d_in[0];
  const float* scene_feats = (const float*)d_in[2];
  const float* prior       = (const float*)d_in[3];
  const float* ln1_g = (const float*)d_in[4];
  const float* ln1_b = (const float*)d_in[5];
  const float* qkv_w = (const float*)d_in[6];
  const float* qkv_b = (const float*)d_in[7];
  const float* out_w = (const float*)d_in[8];
  const float* out_b = (const float*)d_in[9];
  const float* ln2_g = (const float*)d_in[10];
  const float* ln2_b = (const float*)d_in[11];
  const float* ff1_w = (const float*)d_in[12];
  const float* ff1_b = (const float*)d_in[13];
  const float* ff2_w = (const float*)d_in[14];
  const float* ff2_b = (const float*)d_in[15];
  const float* saq_w = (const float*)d_in[16];
  const float* saq_b = (const float*)d_in[17];
  const float* sakv_w = (const float*)d_in[18];
  const float* sakv_b = (const float*)d_in[19];
  const float* saout_w = (const float*)d_in[20];
  const float* saout_b = (const float*)d_in[21];
  const float* fc1_w = (const float*)d_in[22];
  const float* fc1_b = (const float*)d_in[23];
  const float* fc2_w = (const float*)d_in[24];
  const float* fc2_b = (const float*)d_in[25];

  char* W = (char*)d_ws;
  bf16_t* h_bf    = (bf16_t*)(W + MB(0));    // 4 MB
  float*  x_f     = (float*) (W + MB(4));    // 8 MB
  bf16_t* o_ff    = (bf16_t*)(W + MB(12));   // 4 MB  enc-attn out, then ff1g
  bf16_t* qkv_bf  = (bf16_t*)(W + MB(16));   // 12 MB
  bf16_t* qsa     = (bf16_t*)(W + MB(28));   // 4 MB
  bf16_t* sm_bf   = (bf16_t*)(W + MB(32));   // 4 MB
  bf16_t* cat_bf  = (bf16_t*)(W + MB(36));   // 8 MB  [msca | smf]; pre-enc: enc partML
  bf16_t* fc1g    = (bf16_t*)(W + MB(44));   // 16 MB; pre-fc1: enc partO
  bf16_t* vTe     = (bf16_t*)(W + MB(60));   // 4 MB  enc V^T; post-enc: SA partML
  bf16_t* kv_bf   = (bf16_t*)(W + MB(64));   // 64 MB [32768][1024]
  bf16_t* vT      = (bf16_t*)(W + MB(128));  // 32 MB SA V^T  [32 z][128][4096]
  bf16_t* wbase   = (bf16_t*)(W + MB(160));  // 11.5 MB bf16 weights
  bf16_t* scene_bf= (bf16_t*)(W + MB(172));  // 32 MB; post-kv: SA partO (32 MB)

  float* encO  = (float*)fc1g;               // 16 MB (512 tiles x 128x64 f32)
  float* encML = (float*)cat_bf;             // 0.5 MB
  float* saO   = (float*)scene_bf;           // 32 MB (512 tiles x 128x128 f32)
  float* saML  = (float*)vTe;                // 0.5 MB

  bf16_t* wq   = wbase + 0L;
  bf16_t* wout = wbase + 786432L;
  bf16_t* wff1 = wbase + 1048576L;
  bf16_t* wff2 = wbase + 1310720L;
  bf16_t* wsaq = wbase + 1572864L;
  bf16_t* wskv = wbase + 1835008L;
  bf16_t* wsout= wbase + 2359296L;
  bf16_t* wfc1 = wbase + 2621440L;
  bf16_t* wfc2 = wbase + 4718592L;

  const dim3 B256(256);
  const dim3 B512(512);
  auto cvt = [&](const float* s, bf16_t* d, long n) {
    int n4 = (int)(n / 4);
    f2bf_kernel<<<(n4 + 255) / 256, B256, 0, stream>>>((const float4*)s, (ushort4*)d, n4);
  };
  cvt(qkv_w,  wq,   786432);
  cvt(out_w,  wout, 262144);
  cvt(ff1_w,  wff1, 262144);
  cvt(ff2_w,  wff2, 262144);
  cvt(saq_w,  wsaq, 262144);
  cvt(sakv_w, wskv, 524288);
  cvt(saout_w,wsout,262144);
  cvt(fc1_w,  wfc1, 2097152);
  cvt(fc2_w,  wfc2, 1048576);
  cvt(scene_feats, scene_bf, 16777216);

  // 1. h = LN1(motion)
  ln_kernel<<<1024, B256, 0, stream>>>(motion, ln1_g, ln1_b, h_bf);

  // 2. qkv = h @ qkv_w^T + b  [4096,1536]
  { MmaNT p{}; p.scale=1.f; p.zdiv=1; p.cBf=1;
    p.A=h_bf; p.lda=512; p.W=wq; p.ldw=512; p.bias=qkv_b;
    p.C=qkv_bf; p.ldc=1536; p.K=512;
    mma_nt_kernel<128><<<dim3(12,32,1), B256, 0, stream>>>(p); }

  // 3. encoder attention: V^T -> split flash (NS=2, 128-row 8-wave blocks) -> merge
  { TransP t{}; t.src=qkv_bf+1024; t.dst=vTe; t.sSb=786432; t.sSh=64;
    t.ld=1536; t.nh=8; t.N=512; t.D=64;
    transpose_kernel<<<dim3(8,1,64), B256, 0, stream>>>(t); }
  { FlashP2 p{};
    p.Q=qkv_bf;     p.ldq=1536; p.sQb=786432; p.sQh=64;
    p.K=qkv_bf+512; p.ldk=1536; p.sKb=786432; p.sKh=64;
    p.VT=vTe; p.sVz=32768;
    p.prior=nullptr; p.sPb=0;
    p.partO=encO; p.partML=encML;
    p.nh=8; p.N=512; p.segN=256; p.scale=0.125f;
    flash3_kernel<64,0><<<dim3(2,4,64), B512, 0, stream>>>(p); }
  { MergeP m{}; m.partO=encO; m.partML=encML; m.C=o_ff;
    m.ldc=512; m.sCb=262144; m.nh=8; m.y=4;
    fmerge_kernel<64,2><<<256, B256, 0, stream>>>(m); }

  // 4. x = motion + o @ out_w^T + b   (fp32)
  { MmaNT p{}; p.scale=1.f; p.zdiv=1;
    p.A=o_ff; p.lda=512; p.W=wout; p.ldw=512; p.bias=out_b;
    p.res=motion; p.ldr=512;
    p.C=x_f; p.ldc=512; p.K=512;
    mma_nt_kernel<64><<<dim3(4,64,1), B256, 0, stream>>>(p); }

  // 5. h2 = LN2(x)
  ln_kernel<<<1024, B256, 0, stream>>>(x_f, ln2_g, ln2_b, h_bf);

  // 6. ff1g = gelu(h2 @ ff1_w^T + b)
  { MmaNT p{}; p.scale=1.f; p.zdiv=1; p.cBf=1; p.act=1;
    p.A=h_bf; p.lda=512; p.W=wff1; p.ldw=512; p.bias=ff1_b;
    p.C=o_ff; p.ldc=512; p.K=512;
    mma_nt_kernel<64><<<dim3(4,64,1), B256, 0, stream>>>(p); }

  // 7. msca = x + ff1g @ ff2_w^T + b  -> cat[:, 0:512]
  { MmaNT p{}; p.scale=1.f; p.zdiv=1; p.cBf=1;
    p.A=o_ff; p.lda=512; p.W=wff2; p.ldw=512; p.bias=ff2_b;
    p.res=x_f; p.ldr=512;
    p.C=cat_bf; p.ldc=1024; p.K=512;
    mma_nt_kernel<64><<<dim3(4,64,1), B256, 0, stream>>>(p); }

  // 8. q_sa = (msca @ saq_w^T + b) * 512^-0.5
  { MmaNT p{}; p.zdiv=1; p.cBf=1; p.scale=0.04419417382415922f;
    p.A=cat_bf; p.lda=1024; p.W=wsaq; p.ldw=512; p.bias=saq_b;
    p.C=qsa; p.ldc=512; p.K=512;
    mma_nt_kernel<64><<<dim3(4,64,1), B256, 0, stream>>>(p); }

  // 9. kv = scene @ sakv_w^T + b   [32768,1024]
  { MmaNT p{}; p.scale=1.f; p.zdiv=1; p.cBf=1;
    p.A=scene_bf; p.lda=512; p.W=wskv; p.ldw=512; p.bias=sakv_b;
    p.C=kv_bf; p.ldc=1024; p.K=512;
    mma_nt_kernel<128><<<dim3(8,256,1), B256, 0, stream>>>(p); }

  // 10. SA attention: V^T -> split flash (NS=4, 128-row 8-wave blocks) -> merge
  { TransP t{}; t.src=kv_bf+512; t.dst=vT; t.sSb=4194304; t.sSh=128;
    t.ld=1024; t.nh=4; t.N=4096; t.D=128;
    transpose_kernel<<<dim3(64,2,32), B256, 0, stream>>>(t); }
  { FlashP2 p{};
    p.Q=qsa;   p.ldq=128;  p.sQb=262144;  p.sQh=65536;
    p.K=kv_bf; p.ldk=1024; p.sKb=4194304; p.sKh=128;
    p.VT=vT; p.sVz=524288;
    p.prior=prior; p.sPb=2097152;
    p.partO=saO; p.partML=saML;
    p.nh=4; p.N=4096; p.segN=1024; p.scale=1.f;
    flash3_kernel<128,1><<<dim3(4,4,32), B512, 0, stream>>>(p); }
  { MergeP m{}; m.partO=saO; m.partML=saML; m.C=sm_bf;
    m.ldc=512; m.sCb=262144; m.nh=4; m.y=4;
    fmerge_kernel<128,4><<<128, B256, 0, stream>>>(m); }

  // 11. smf = sm @ saout_w^T + b  -> cat[:, 512:1024]
  { MmaNT p{}; p.scale=1.f; p.zdiv=1; p.cBf=1;
    p.A=sm_bf; p.lda=512; p.W=wsout; p.ldw=512; p.bias=saout_b;
    p.C=cat_bf + 512; p.ldc=1024; p.K=512;
    mma_nt_kernel<64><<<dim3(4,64,1), B256, 0, stream>>>(p); }

  // 12. fc1g = gelu(cat @ fc1_w^T + b)   [4096,2048]
  { MmaNT p{}; p.scale=1.f; p.zdiv=1; p.cBf=1; p.act=1;
    p.A=cat_bf; p.lda=1024; p.W=wfc1; p.ldw=1024; p.bias=fc1_b;
    p.C=fc1g; p.ldc=2048; p.K=1024;
    mma_nt_kernel<128><<<dim3(16,32,1), B256, 0, stream>>>(p); }

  // 13. out = fc1g @ fc2_w^T + b  -> d_out fp32
  { MmaNT p{}; p.scale=1.f; p.zdiv=1;
    p.A=fc1g; p.lda=2048; p.W=wfc2; p.ldw=2048; p.bias=fc2_b;
    p.C=d_out; p.ldc=512; p.K=2048;
    mma_nt_kernel<64><<<dim3(4,64,1), B256, 0, stream>>>(p); }
}

// Round 13
// 648.908 us; speedup vs baseline: 1.0148x; 1.0148x over previous
//
#include <hip/hip_runtime.h>

typedef unsigned short bf16_t;
typedef __attribute__((ext_vector_type(8))) short bf16x8;
typedef __attribute__((ext_vector_type(4))) float f32x4;

// ---------------- conversions ----------------
__device__ __forceinline__ float bf2f(bf16_t u) {
  union { unsigned int i; float f; } v; v.i = ((unsigned int)u) << 16; return v.f;
}
__device__ __forceinline__ bf16_t f2bf(float f) {
  union { float f; unsigned int i; } v; v.f = f;
  unsigned int u = v.i;
  u += 0x7fffu + ((u >> 16) & 1u);   // RNE
  return (bf16_t)(u >> 16);
}
__device__ __forceinline__ float gelu_exact(float x) {
  return 0.5f * x * (1.0f + erff(x * 0.7071067811865475f));
}
// async global->LDS 16B copy: per-wave, lane l's 16B lands at lds_base + l*16
__device__ __forceinline__ void g2l16(bf16_t* l, const bf16_t* g) {
  __builtin_amdgcn_global_load_lds(
      (const __attribute__((address_space(1))) unsigned int*)g,
      (__attribute__((address_space(3))) unsigned int*)l, 16, 0, 0);
}

// ---------------- fp32 -> bf16 convert ----------------
__global__ __launch_bounds__(256) void f2bf_kernel(const float4* __restrict__ s,
                                                   ushort4* __restrict__ d, int n4) {
  int i = blockIdx.x * 256 + threadIdx.x;
  if (i < n4) {
    float4 f = s[i];
    ushort4 u; u.x = f2bf(f.x); u.y = f2bf(f.y); u.z = f2bf(f.z); u.w = f2bf(f.w);
    d[i] = u;
  }
}

// ---------------- LayerNorm: one wave per row of 512, fp32 in -> bf16 out ----------------
__global__ __launch_bounds__(256) void ln_kernel(const float* __restrict__ x,
                                                 const float* __restrict__ g,
                                                 const float* __restrict__ bta,
                                                 bf16_t* __restrict__ y) {
  const int w = threadIdx.x >> 6, lane = threadIdx.x & 63;
  const long row = (long)blockIdx.x * 4 + w;
  const long base = row * 512;
  const int c0 = lane << 2;
  float v[8];
  float4 f0 = *(const float4*)(x + base + c0);
  float4 f1 = *(const float4*)(x + base + 256 + c0);
  v[0]=f0.x; v[1]=f0.y; v[2]=f0.z; v[3]=f0.w;
  v[4]=f1.x; v[5]=f1.y; v[6]=f1.z; v[7]=f1.w;
  float s = 0.f;
#pragma unroll
  for (int c=0;c<8;++c) s += v[c];
#pragma unroll
  for (int o=32;o>0;o>>=1) s += __shfl_xor(s, o);
  const float mean = s * 0.001953125f;
  float ss = 0.f;
#pragma unroll
  for (int c=0;c<8;++c) { float d = v[c]-mean; ss += d*d; }
#pragma unroll
  for (int o=32;o>0;o>>=1) ss += __shfl_xor(ss, o);
  const float rstd = rsqrtf(ss * 0.001953125f + 1e-5f);
  ushort4 o0, o1;
  o0.x = f2bf((v[0]-mean)*rstd*g[c0+0] + bta[c0+0]);
  o0.y = f2bf((v[1]-mean)*rstd*g[c0+1] + bta[c0+1]);
  o0.z = f2bf((v[2]-mean)*rstd*g[c0+2] + bta[c0+2]);
  o0.w = f2bf((v[3]-mean)*rstd*g[c0+3] + bta[c0+3]);
  o1.x = f2bf((v[4]-mean)*rstd*g[256+c0+0] + bta[256+c0+0]);
  o1.y = f2bf((v[5]-mean)*rstd*g[256+c0+1] + bta[256+c0+1]);
  o1.z = f2bf((v[6]-mean)*rstd*g[256+c0+2] + bta[256+c0+2]);
  o1.w = f2bf((v[7]-mean)*rstd*g[256+c0+3] + bta[256+c0+3]);
  *(ushort4*)(y + base + c0) = o0;
  *(ushort4*)(y + base + 256 + c0) = o1;
}

// ---------------- MFMA GEMM  C = A @ W^T  (bf16 in, +bias/gelu/scale/+res fp32) ------------
// MT=128: m97 structure — global_load_lds staging A[128][32]+W[128][32], 2 barriers/K-step.
// MT=64 : direct global->reg fragment loads, 2-deep prefetch.
// XCD-aware block swizzle: the n-blocks sharing an A panel land on one XCD's L2.
struct MmaNT {
  const bf16_t* A; const bf16_t* W; const float* bias; const float* res; void* C;
  long lda, sAb, sAh;
  long ldw, sWb, sWh;
  long ldr, sRb, sRh;
  long ldc, sCb, sCh;
  int K, zdiv, cBf, act;
  float scale;
};

template <int MT>
__global__ __launch_bounds__(256) void mma_nt_kernel(MmaNT p) {
  constexpr int FM = MT / 32;          // m-frags per wave (wave covers MT/2 rows)
  constexpr int TILE_E = (MT + 128) * 32;     // A+W staging tiles (bf16 elems)
  constexpr int ST_E = MT * 128;              // epilogue staging
  constexpr int SM_E = (TILE_E > ST_E) ? TILE_E : ST_E;
  __shared__ __align__(16) bf16_t smem[SM_E];
  bf16_t* Al = smem;
  bf16_t* Wl = smem + MT * 32;
  const int tid = threadIdx.x;
  const int wid = tid >> 6, lane = tid & 63;
  const int wm = wid & 1, wn = wid >> 1;     // waves 2x2 over (M/2, 128/2)
  const int quad = lane >> 4, l16 = lane & 15;
  const int z = blockIdx.z;
  const int zb = z / p.zdiv, zh = z % p.zdiv;

  // bijective XCD swizzle (all grids are multiples of 8 workgroups, z==1 for GEMMs)
  const int nbx = gridDim.x;
  const int nwg = nbx * gridDim.y;
  const int flat = blockIdx.y * nbx + blockIdx.x;
  const int sw = (flat & 7) * (nwg >> 3) + (flat >> 3);
  const int bx = sw % nbx, by = sw / nbx;

  const long m0 = (long)by * MT;
  const long n0 = (long)bx * 128;

  f32x4 zero4 = {0.f, 0.f, 0.f, 0.f};
  f32x4 acc[FM][4];
#pragma unroll
  for (int fm = 0; fm < FM; ++fm)
#pragma unroll
    for (int fn = 0; fn < 4; ++fn) acc[fm][fn] = zero4;

  if constexpr (MT == 128) {
    // ---- async-DMA staged K-loop (m97 structure) ----
    const bf16_t* Ag = p.A + (long)zb * p.sAb + (long)zh * p.sAh + m0 * p.lda;
    const bf16_t* Wg = p.W + (long)zb * p.sWb + (long)zh * p.sWh + n0 * p.ldw;
    const int sr = lane >> 2;           // lane's row within a 16-row wave group
    const int sc = (lane & 3) * 8;      // lane's col group (8 bf16 = 16B)
    for (int kc = 0; kc < p.K; kc += 32) {
      // stage A tile [128][32]: 2 calls x (4 waves x 16 rows)
#pragma unroll
      for (int j = 0; j < 2; ++j)
        g2l16(&Al[(j * 64 + wid * 16) * 32],
              Ag + (long)(j * 64 + wid * 16 + sr) * p.lda + kc + sc);
      // stage W tile [128][32]
#pragma unroll
      for (int j = 0; j < 2; ++j)
        g2l16(&Wl[(j * 64 + wid * 16) * 32],
              Wg + (long)(j * 64 + wid * 16 + sr) * p.ldw + kc + sc);
      __syncthreads();   // drains DMA (vmcnt) + sync
      bf16x8 af[FM], wf[4];
#pragma unroll
      for (int fm = 0; fm < FM; ++fm)
        af[fm] = *(const bf16x8*)&Al[(wm * 64 + fm * 16 + l16) * 32 + quad * 8];
#pragma unroll
      for (int fn = 0; fn < 4; ++fn)
        wf[fn] = *(const bf16x8*)&Wl[(wn * 64 + fn * 16 + l16) * 32 + quad * 8];
#pragma unroll
      for (int fm = 0; fm < FM; ++fm)
#pragma unroll
        for (int fn = 0; fn < 4; ++fn)
          acc[fm][fn] = __builtin_amdgcn_mfma_f32_16x16x32_bf16(af[fm], wf[fn], acc[fm][fn], 0, 0, 0);
      __syncthreads();   // all reads done before next stage overwrites
    }
  } else {
    // ---- direct-to-reg K-loop, 2-deep prefetch (K is a multiple of 64) ----
    const bf16_t* Ag = p.A + (long)zb * p.sAb + (long)zh * p.sAh +
                       (m0 + wm * (MT / 2) + l16) * p.lda;
    const bf16_t* Wg = p.W + (long)zb * p.sWb + (long)zh * p.sWh +
                       (n0 + wn * 64 + l16) * p.ldw;
    bf16x8 a0[FM], w0[4], a1[FM], w1[4], an0[FM], wn0[4], an1[FM], wn1[4];
#pragma unroll
    for (int fm = 0; fm < FM; ++fm) {
      a0[fm] = *(const bf16x8*)(Ag + (long)(fm * 16) * p.lda + quad * 8);
      a1[fm] = *(const bf16x8*)(Ag + (long)(fm * 16) * p.lda + 32 + quad * 8);
    }
#pragma unroll
    for (int fn = 0; fn < 4; ++fn) {
      w0[fn] = *(const bf16x8*)(Wg + (long)(fn * 16) * p.ldw + quad * 8);
      w1[fn] = *(const bf16x8*)(Wg + (long)(fn * 16) * p.ldw + 32 + quad * 8);
    }
    for (int kc = 0; kc < p.K; kc += 64) {
      int k2 = kc + 64;
      if (k2 > p.K - 64) k2 = p.K - 64;   // clamp: last-iter loads redundant but safe
      // issue loads for step kc+64 (covered by the two MFMA phases below)
#pragma unroll
      for (int fm = 0; fm < FM; ++fm)
        an0[fm] = *(const bf16x8*)(Ag + (long)(fm * 16) * p.lda + k2 + quad * 8);
#pragma unroll
      for (int fn = 0; fn < 4; ++fn)
        wn0[fn] = *(const bf16x8*)(Wg + (long)(fn * 16) * p.ldw + k2 + quad * 8);
#pragma unroll
      for (int fm = 0; fm < FM; ++fm)
#pragma unroll
        for (int fn = 0; fn < 4; ++fn)
          acc[fm][fn] = __builtin_amdgcn_mfma_f32_16x16x32_bf16(a0[fm], w0[fn], acc[fm][fn], 0, 0, 0);
      // issue loads for step kc+96
#pragma unroll
      for (int fm = 0; fm < FM; ++fm)
        an1[fm] = *(const bf16x8*)(Ag + (long)(fm * 16) * p.lda + k2 + 32 + quad * 8);
#pragma unroll
      for (int fn = 0; fn < 4; ++fn)
        wn1[fn] = *(const bf16x8*)(Wg + (long)(fn * 16) * p.ldw + k2 + 32 + quad * 8);
#pragma unroll
      for (int fm = 0; fm < FM; ++fm)
#pragma unroll
        for (int fn = 0; fn < 4; ++fn)
          acc[fm][fn] = __builtin_amdgcn_mfma_f32_16x16x32_bf16(a1[fm], w1[fn], acc[fm][fn], 0, 0, 0);
#pragma unroll
      for (int fm = 0; fm < FM; ++fm) { a0[fm] = an0[fm]; a1[fm] = an1[fm]; }
#pragma unroll
      for (int fn = 0; fn < 4; ++fn) { w0[fn] = wn0[fn]; w1[fn] = wn1[fn]; }
    }
  }

  const long cOff = (long)zb * p.sCb + (long)zh * p.sCh;
  const long rOff = (long)zb * p.sRb + (long)zh * p.sRh;
  if (p.cBf) {
    // ---- staged epilogue: postprocess -> LDS [MT][128] -> coalesced uint4 stores ----
#pragma unroll
    for (int fm = 0; fm < FM; ++fm) {
#pragma unroll
      for (int fn = 0; fn < 4; ++fn) {
        const int lc = wn * 64 + fn * 16 + l16;
        const long col = n0 + lc;
        const float bv = p.bias ? p.bias[col] : 0.f;
#pragma unroll
        for (int r = 0; r < 4; ++r) {
          const int lr = wm * (MT / 2) + fm * 16 + quad * 4 + r;
          float t = acc[fm][fn][r] + bv;
          if (p.act) t = gelu_exact(t);
          t *= p.scale;
          if (p.res) t += p.res[rOff + (m0 + lr) * p.ldr + col];
          smem[lr * 128 + lc] = f2bf(t);
        }
      }
    }
    __syncthreads();
    bf16_t* Cg = (bf16_t*)p.C + cOff + m0 * p.ldc + n0;
#pragma unroll
    for (int i = 0; i < MT / 16; ++i) {     // MT rows x 16 chunks(16B)/row
      const int flat2 = tid + i * 256;
      const int r = flat2 >> 4, c = (flat2 & 15) * 8;
      *(uint4*)(Cg + (long)r * p.ldc + c) = *(const uint4*)&smem[r * 128 + c];
    }
  } else {
    // fp32 output path (MT=64 launches only) — direct stores
#pragma unroll
    for (int fm = 0; fm < FM; ++fm) {
#pragma unroll
      for (int fn = 0; fn < 4; ++fn) {
        const long col = n0 + wn * 64 + fn * 16 + l16;
        const float bv = p.bias ? p.bias[col] : 0.f;
#pragma unroll
        for (int r = 0; r < 4; ++r) {
          const long row = m0 + wm * (MT / 2) + fm * 16 + quad * 4 + r;
          float t = acc[fm][fn][r] + bv;
          if (p.act) t = gelu_exact(t);
          t *= p.scale;
          if (p.res) t += p.res[rOff + row * p.ldr + col];
          ((float*)p.C)[cOff + row * p.ldc + col] = t;
        }
      }
    }
  }
}

// ---------------- tile transpose: per z, [N][D] slice (ld) -> [D][N] dst ----------------
struct TransP {
  const bf16_t* src; bf16_t* dst;
  long sSb, sSh, ld;
  int nh, N, D;
};

__global__ __launch_bounds__(256) void transpose_kernel(TransP p) {
  __shared__ bf16_t T[64][72];
  const int tid = threadIdx.x;
  const int z = blockIdx.z;
  const int zb = z / p.nh, zh = z % p.nh;
  const long n0 = (long)blockIdx.x * 64;
  const long d0 = (long)blockIdx.y * 64;
  const bf16_t* src = p.src + (long)zb * p.sSb + (long)zh * p.sSh;
  bf16_t* dst = p.dst + (long)z * p.D * p.N;
#pragma unroll
  for (int i = 0; i < 2; ++i) {
    int flat = tid + i * 256, r = flat >> 3, cg = flat & 7;
    uint4 v = *(const uint4*)(src + (n0 + r) * p.ld + d0 + cg * 8);
    *(uint4*)&T[r][cg * 8] = v;
  }
  __syncthreads();
#pragma unroll
  for (int i = 0; i < 2; ++i) {
    int flat = tid + i * 256, dr = flat >> 3, ncg = flat & 7;
    uint4 o;
    unsigned int* op = (unsigned int*)&o;
#pragma unroll
    for (int j = 0; j < 4; ++j)
      op[j] = (unsigned int)T[ncg * 8 + 2 * j][dr] | ((unsigned int)T[ncg * 8 + 2 * j + 1][dr] << 16);
    *(uint4*)(dst + (d0 + dr) * p.N + n0 + ncg * 8) = o;
  }
}

// ---------------- split-KV flash attention, DMA double-buffered pipeline (pass 1) ---------
// Block: 128 q-rows (8 waves x 16), one (b,h), one N-segment; k-tile = 64 N-rows.
// T3 minimum 2-phase: tile t+1's DMA issues at the TOP of iter t into the alternate
// LDS buffer pair; the bottom __syncthreads' vmcnt(0) drain is covered by the whole
// compute phase. 1 barrier/iter, drain ~free. LDS 82 KB (DH=128) -> 1 block/CU.
// Prior double-buffered in regs (pr0/pr1); defer-max (THR=8) skips the O/l rescale.
struct FlashP2 {
  const bf16_t* Q; const bf16_t* K; const bf16_t* VT; const float* prior;
  float* partO; float* partML;
  long ldq, sQb, sQh;
  long ldk, sKb, sKh;
  long sVz, sPb;
  int nh, N, segN;
  float scale;
};

template <int DH, int HASP>
__global__ __launch_bounds__(512) void flash3_kernel(FlashP2 p) {
  constexpr int KK = DH / 32;       // k-frags over dh (QK^T)
  constexpr int NFO = DH / 16;      // output col frags
  constexpr int KE = 64 * DH;       // Kl elems (linear [64][DH])
  constexpr int VE = DH * 64;       // Vl elems (linear [DH][64])
  constexpr int PE = 128 * 72;      // Pl elems [128 q-rows][72]
  __shared__ __align__(16) bf16_t smem[2 * KE + 2 * VE + PE];
  bf16_t* Kl0 = smem;
  bf16_t* Kl1 = smem + KE;
  bf16_t* Vl0 = smem + 2 * KE;
  bf16_t* Vl1 = smem + 2 * KE + VE;
  bf16_t* Pl  = smem + 2 * KE + 2 * VE;
  const int tid = threadIdx.x;
  const int w = tid >> 6, lane = tid & 63;      // 8 waves
  const int quad = lane >> 4, l16 = lane & 15;
  const int z = blockIdx.z;
  const int zb = z / p.nh, zh = z % p.nh;
  const int qr0 = blockIdx.y * 128 + w * 16;    // wave's first q-row
  const bf16_t* Q = p.Q + (long)zb * p.sQb + (long)zh * p.sQh + (long)qr0 * p.ldq;
  const bf16_t* K = p.K + (long)zb * p.sKb + (long)zh * p.sKh;
  const bf16_t* VT = p.VT + (long)z * p.sVz;

  // persistent Q A-frags (16 q-rows per wave)
  bf16x8 qf[KK];
#pragma unroll
  for (int kk = 0; kk < KK; ++kk)
    qf[kk] = *(const bf16x8*)(Q + (long)l16 * p.ldq + kk * 32 + quad * 8);

  f32x4 zero4 = {0.f, 0.f, 0.f, 0.f};
  f32x4 O[NFO];
  float m_[4], l_[4];
#pragma unroll
  for (int f = 0; f < NFO; ++f) O[f] = zero4;
#pragma unroll
  for (int r = 0; r < 4; ++r) { m_[r] = -1e30f; l_[r] = 0.f; }

  // staging geometry (8 waves)
  constexpr int LPR = DH / 8;       // lanes per K row
  constexpr int RPC = 512 / DH;     // K rows per 1024B DMA call
  constexpr int KCW = (64 / RPC) / 8;    // K calls per wave (DH=128:2, DH=64:1)
  constexpr int VCW = (DH / 8) / 8;      // V calls per wave (DH=128:2, DH=64:1)
  const int krl = lane / LPR;            // K: lane's row within a call group
  const int kcb = (lane % LPR) * 16;     // K: lane's byte col
  const int vrl = lane >> 3;             // V: 8 lanes per 128B row
  const int vcb = (lane & 7) * 16;

  const float* PRrow = HASP ? (p.prior + (long)zb * p.sPb +
                               (long)(qr0 + quad * 4) * p.N) : (const float*)nullptr;

  const int k0 = blockIdx.x * p.segN;
  const int kend = k0 + p.segN;     // segN is a multiple of 128 for all launches

  auto stage = [&](bf16_t* Kl, bf16_t* Vl, int ktc) {
#pragma unroll
    for (int j = 0; j < KCW; ++j) {
      const int R0 = (w + 8 * j) * RPC;
      const int r = R0 + krl;
      const int cs = kcb ^ ((r & 7) << 4);
      g2l16(&Kl[R0 * DH], K + (long)(ktc + r) * p.ldk + (cs >> 1));
    }
#pragma unroll
    for (int j = 0; j < VCW; ++j) {
      const int R0 = (w + 8 * j) * 8;
      const int r = R0 + vrl;
      const int cs = vcb ^ ((r & 7) << 4);
      g2l16(&Vl[R0 * 64], VT + (long)r * p.N + ktc + (cs >> 1));
    }
  };

  auto loadprior = [&](int kn, float (&dst)[4][4]) {
    if (kn > p.N - 64) kn = p.N - 64;   // clamp (values unused past end)
#pragma unroll
    for (int nf = 0; nf < 4; ++nf)
#pragma unroll
      for (int r = 0; r < 4; ++r)
        dst[nf][r] = PRrow[(long)r * p.N + kn + nf * 16 + l16];
  };

  auto body = [&](const bf16_t* Kl, const bf16_t* Vl, float (&prC)[4][4]) {
    // ---- S = Q K^T (kf from swizzled Kl) ----
    f32x4 s[4];
#pragma unroll
    for (int nf = 0; nf < 4; ++nf) s[nf] = zero4;
#pragma unroll
    for (int nf = 0; nf < 4; ++nf)
#pragma unroll
      for (int kk = 0; kk < KK; ++kk) {
        bf16x8 kf = *(const bf16x8*)&Kl[(nf * 16 + l16) * DH +
                                        ((kk * 32 + quad * 8) ^ ((l16 & 7) << 3))];
        s[nf] = __builtin_amdgcn_mfma_f32_16x16x32_bf16(qf[kk], kf, s[nf], 0, 0, 0);
      }
    // ---- scale + prior, tile row-max ----
    float tm[4];
#pragma unroll
    for (int r = 0; r < 4; ++r) tm[r] = -1e30f;
#pragma unroll
    for (int nf = 0; nf < 4; ++nf)
#pragma unroll
      for (int r = 0; r < 4; ++r) {
        float t = s[nf][r] * p.scale;
        if (HASP) t += prC[nf][r];
        s[nf][r] = t;
        tm[r] = fmaxf(tm[r], t);
      }
#pragma unroll
    for (int off = 1; off < 16; off <<= 1)
#pragma unroll
      for (int r = 0; r < 4; ++r) tm[r] = fmaxf(tm[r], __shfl_xor(tm[r], off));
    // ---- online softmax, defer-max (skip rescale when max doesn't grow) ----
    const int ok = (tm[0] <= m_[0] + 8.f) && (tm[1] <= m_[1] + 8.f) &&
                   (tm[2] <= m_[2] + 8.f) && (tm[3] <= m_[3] + 8.f);
    if (!__all(ok)) {
      float alpha[4];
#pragma unroll
      for (int r = 0; r < 4; ++r) {
        float mn = fmaxf(m_[r], tm[r]);
        alpha[r] = __expf(m_[r] - mn);
        m_[r] = mn;
        l_[r] *= alpha[r];
      }
#pragma unroll
      for (int f = 0; f < NFO; ++f)
#pragma unroll
        for (int r = 0; r < 4; ++r) O[f][r] *= alpha[r];
    }
    float rs[4];
#pragma unroll
    for (int r = 0; r < 4; ++r) rs[r] = 0.f;
#pragma unroll
    for (int nf = 0; nf < 4; ++nf)
#pragma unroll
      for (int r = 0; r < 4; ++r) {
        float pv = __expf(s[nf][r] - m_[r]);   // bounded by e^8 under defer
        s[nf][r] = pv;
        rs[r] += pv;
      }
#pragma unroll
    for (int off = 1; off < 16; off <<= 1)
#pragma unroll
      for (int r = 0; r < 4; ++r) rs[r] += __shfl_xor(rs[r], off);
#pragma unroll
    for (int r = 0; r < 4; ++r) l_[r] += rs[r];
    // ---- P: C-layout -> LDS (wave-private rows) -> A-layout ----
#pragma unroll
    for (int nf = 0; nf < 4; ++nf)
#pragma unroll
      for (int r = 0; r < 4; ++r)
        Pl[(w * 16 + quad * 4 + r) * 72 + nf * 16 + l16] = f2bf(s[nf][r]);
    bf16x8 pf[2];
#pragma unroll
    for (int kk2 = 0; kk2 < 2; ++kk2)
      pf[kk2] = *(const bf16x8*)&Pl[(w * 16 + l16) * 72 + kk2 * 32 + quad * 8];
#pragma unroll
    for (int f = 0; f < NFO; ++f)
#pragma unroll
      for (int kk2 = 0; kk2 < 2; ++kk2) {
        bf16x8 vf = *(const bf16x8*)&Vl[(f * 16 + l16) * 64 +
                                        ((kk2 * 32 + quad * 8) ^ ((l16 & 7) << 3))];
        O[f] = __builtin_amdgcn_mfma_f32_16x16x32_bf16(pf[kk2], vf, O[f], 0, 0, 0);
      }
  };

  float pr0[4][4], pr1[4][4];
  // ---- prologue: stage tile k0 into buf0; drain ----
  stage(Kl0, Vl0, k0);
  if (HASP) loadprior(k0, pr0);
  __syncthreads();

  for (int kt = k0; kt < kend; kt += 128) {
    // phase A: stage t+1 into buf1 (drains at bottom barrier, covered by compute)
    stage(Kl1, Vl1, kt + 64);
    if (HASP) loadprior(kt + 64, pr1);
    body(Kl0, Vl0, pr0);
    __syncthreads();
    // phase B: stage t+2 into buf0
    if (kt + 128 < kend) stage(Kl0, Vl0, kt + 128);
    if (HASP) loadprior(kt + 128, pr0);
    body(Kl1, Vl1, pr1);
    __syncthreads();
  }

  // ---- write partials (128 q-rows per tile) ----
  const long t = ((long)z * gridDim.y + blockIdx.y) * gridDim.x + blockIdx.x;
  float* PO = p.partO + t * (128 * DH);
  float* PM = p.partML + t * 256;
  const int row = w * 16 + quad * 4;
#pragma unroll
  for (int f = 0; f < NFO; ++f)
#pragma unroll
    for (int r = 0; r < 4; ++r)
      PO[(long)(row + r) * DH + f * 16 + l16] = O[f][r];
  if (l16 == 0) {
#pragma unroll
    for (int r = 0; r < 4; ++r) {
      PM[(row + r) * 2 + 0] = m_[r];
      PM[(row + r) * 2 + 1] = l_[r];
    }
  }
}

// ---------------- flash pass 2: merge NS segment partials, normalize, store bf16 ----------
// 128-row tiles; 256 threads = 128 rows x 2 col-halves.
struct MergeP {
  const float* partO; const float* partML; bf16_t* C;
  long ldc, sCb;
  int nh, y;
};

template <int DH, int NS>
__global__ __launch_bounds__(256) void fmerge_kernel(MergeP p) {
  const int tid = threadIdx.x;
  const int r = tid >> 1, ch = tid & 1;          // 128 rows x 2 col-halves
  const int blk = blockIdx.x;
  const int z = blk / p.y, qb = blk % p.y;
  const int zb = z / p.nh, zh = z % p.nh;
  const long t0 = (long)blk * NS;
  float mm[NS], wgt[NS];
  float mstar = -1e30f;
#pragma unroll
  for (int s = 0; s < NS; ++s) {
    mm[s] = p.partML[(t0 + s) * 256 + r * 2];
    mstar = fmaxf(mstar, mm[s]);
  }
  float lsum = 0.f;
#pragma unroll
  for (int s = 0; s < NS; ++s) {
    wgt[s] = __expf(mm[s] - mstar);
    lsum += wgt[s] * p.partML[(t0 + s) * 256 + r * 2 + 1];
  }
  const float inv = 1.0f / lsum;
  const int c0 = ch * (DH / 2);
  bf16_t* Cp = p.C + (long)zb * p.sCb + (long)(qb * 128 + r) * p.ldc + (long)zh * DH + c0;
#pragma unroll
  for (int c = 0; c < DH / 2; c += 4) {
    float4 acc = make_float4(0.f, 0.f, 0.f, 0.f);
#pragma unroll
    for (int s = 0; s < NS; ++s) {
      float4 v = *(const float4*)(p.partO + (t0 + s) * (128 * DH) + (long)r * DH + c0 + c);
      acc.x += wgt[s] * v.x; acc.y += wgt[s] * v.y;
      acc.z += wgt[s] * v.z; acc.w += wgt[s] * v.w;
    }
    ushort4 o;
    o.x = f2bf(acc.x * inv); o.y = f2bf(acc.y * inv);
    o.z = f2bf(acc.z * inv); o.w = f2bf(acc.w * inv);
    *(ushort4*)(Cp + c) = o;
  }
}

// ---------------- host ----------------
#define MB(x) ((long)(x) << 20)

extern "C" void kernel_launch(void* const* d_in, const int* in_sizes, int n_in,
                              void* d_out, int out_size, void* d_ws, size_t ws_size,
                              hipStream_t stream) {
  const float* motion      = (const float*)d_in[0];
  const float* scene_feats = (const float*)d_in[2];
  const float* prior       = (const float*)d_in[3];
  const float* ln1_g = (const float*)d_in[4];
  const float* ln1_b = (const float*)d_in[5];
  const float* qkv_w = (const float*)d_in[6];
  const float* qkv_b = (const float*)d_in[7];
  const float* out_w = (const float*)d_in[8];
  const float* out_b = (const float*)d_in[9];
  const float* ln2_g = (const float*)d_in[10];
  const float* ln2_b = (const float*)d_in[11];
  const float* ff1_w = (const float*)d_in[12];
  const float* ff1_b = (const float*)d_in[13];
  const float* ff2_w = (const float*)d_in[14];
  const float* ff2_b = (const float*)d_in[15];
  const float* saq_w = (const float*)d_in[16];
  const float* saq_b = (const float*)d_in[17];
  const float* sakv_w = (const float*)d_in[18];
  const float* sakv_b = (const float*)d_in[19];
  const float* saout_w = (const float*)d_in[20];
  const float* saout_b = (const float*)d_in[21];
  const float* fc1_w = (const float*)d_in[22];
  const float* fc1_b = (const float*)d_in[23];
  const float* fc2_w = (const float*)d_in[24];
  const float* fc2_b = (const float*)d_in[25];

  char* W = (char*)d_ws;
  bf16_t* h_bf    = (bf16_t*)(W + MB(0));    // 4 MB
  float*  x_f     = (float*) (W + MB(4));    // 8 MB
  bf16_t* o_ff    = (bf16_t*)(W + MB(12));   // 4 MB  enc-attn out, then ff1g
  bf16_t* qkv_bf  = (bf16_t*)(W + MB(16));   // 12 MB
  bf16_t* qsa     = (bf16_t*)(W + MB(28));   // 4 MB
  bf16_t* sm_bf   = (bf16_t*)(W + MB(32));   // 4 MB
  bf16_t* cat_bf  = (bf16_t*)(W + MB(36));   // 8 MB  [msca | smf]; pre-enc: enc partML
  bf16_t* fc1g    = (bf16_t*)(W + MB(44));   // 16 MB; pre-fc1: enc partO
  bf16_t* vTe     = (bf16_t*)(W + MB(60));   // 4 MB  enc V^T; post-enc: SA partML
  bf16_t* kv_bf   = (bf16_t*)(W + MB(64));   // 64 MB [32768][1024]
  bf16_t* vT      = (bf16_t*)(W + MB(128));  // 32 MB SA V^T  [32 z][128][4096]
  bf16_t* wbase   = (bf16_t*)(W + MB(160));  // 11.5 MB bf16 weights
  bf16_t* scene_bf= (bf16_t*)(W + MB(172));  // 32 MB; post-kv: SA partO (32 MB)

  float* encO  = (float*)fc1g;               // 16 MB (512 tiles x 128x64 f32)
  float* encML = (float*)cat_bf;             // 0.5 MB
  float* saO   = (float*)scene_bf;           // 32 MB (512 tiles x 128x128 f32)
  float* saML  = (float*)vTe;                // 0.5 MB

  bf16_t* wq   = wbase + 0L;
  bf16_t* wout = wbase + 786432L;
  bf16_t* wff1 = wbase + 1048576L;
  bf16_t* wff2 = wbase + 1310720L;
  bf16_t* wsaq = wbase + 1572864L;
  bf16_t* wskv = wbase + 1835008L;
  bf16_t* wsout= wbase + 2359296L;
  bf16_t* wfc1 = wbase + 2621440L;
  bf16_t* wfc2 = wbase + 4718592L;

  const dim3 B256(256);
  const dim3 B512(512);
  auto cvt = [&](const float* s, bf16_t* d, long n) {
    int n4 = (int)(n / 4);
    f2bf_kernel<<<(n4 + 255) / 256, B256, 0, stream>>>((const float4*)s, (ushort4*)d, n4);
  };
  cvt(qkv_w,  wq,   786432);
  cvt(out_w,  wout, 262144);
  cvt(ff1_w,  wff1, 262144);
  cvt(ff2_w,  wff2, 262144);
  cvt(saq_w,  wsaq, 262144);
  cvt(sakv_w, wskv, 524288);
  cvt(saout_w,wsout,262144);
  cvt(fc1_w,  wfc1, 2097152);
  cvt(fc2_w,  wfc2, 1048576);
  cvt(scene_feats, scene_bf, 16777216);

  // 1. h = LN1(motion)
  ln_kernel<<<1024, B256, 0, stream>>>(motion, ln1_g, ln1_b, h_bf);

  // 2. qkv = h @ qkv_w^T + b  [4096,1536]
  { MmaNT p{}; p.scale=1.f; p.zdiv=1; p.cBf=1;
    p.A=h_bf; p.lda=512; p.W=wq; p.ldw=512; p.bias=qkv_b;
    p.C=qkv_bf; p.ldc=1536; p.K=512;
    mma_nt_kernel<128><<<dim3(12,32,1), B256, 0, stream>>>(p); }

  // 3. encoder attention: V^T -> split flash (NS=2, 128-row 8-wave pipelined) -> merge
  { TransP t{}; t.src=qkv_bf+1024; t.dst=vTe; t.sSb=786432; t.sSh=64;
    t.ld=1536; t.nh=8; t.N=512; t.D=64;
    transpose_kernel<<<dim3(8,1,64), B256, 0, stream>>>(t); }
  { FlashP2 p{};
    p.Q=qkv_bf;     p.ldq=1536; p.sQb=786432; p.sQh=64;
    p.K=qkv_bf+512; p.ldk=1536; p.sKb=786432; p.sKh=64;
    p.VT=vTe; p.sVz=32768;
    p.prior=nullptr; p.sPb=0;
    p.partO=encO; p.partML=encML;
    p.nh=8; p.N=512; p.segN=256; p.scale=0.125f;
    flash3_kernel<64,0><<<dim3(2,4,64), B512, 0, stream>>>(p); }
  { MergeP m{}; m.partO=encO; m.partML=encML; m.C=o_ff;
    m.ldc=512; m.sCb=262144; m.nh=8; m.y=4;
    fmerge_kernel<64,2><<<256, B256, 0, stream>>>(m); }

  // 4. x = motion + o @ out_w^T + b   (fp32)
  { MmaNT p{}; p.scale=1.f; p.zdiv=1;
    p.A=o_ff; p.lda=512; p.W=wout; p.ldw=512; p.bias=out_b;
    p.res=motion; p.ldr=512;
    p.C=x_f; p.ldc=512; p.K=512;
    mma_nt_kernel<64><<<dim3(4,64,1), B256, 0, stream>>>(p); }

  // 5. h2 = LN2(x)
  ln_kernel<<<1024, B256, 0, stream>>>(x_f, ln2_g, ln2_b, h_bf);

  // 6. ff1g = gelu(h2 @ ff1_w^T + b)
  { MmaNT p{}; p.scale=1.f; p.zdiv=1; p.cBf=1; p.act=1;
    p.A=h_bf; p.lda=512; p.W=wff1; p.ldw=512; p.bias=ff1_b;
    p.C=o_ff; p.ldc=512; p.K=512;
    mma_nt_kernel<64><<<dim3(4,64,1), B256, 0, stream>>>(p); }

  // 7. msca = x + ff1g @ ff2_w^T + b  -> cat[:, 0:512]
  { MmaNT p{}; p.scale=1.f; p.zdiv=1; p.cBf=1;
    p.A=o_ff; p.lda=512; p.W=wff2; p.ldw=512; p.bias=ff2_b;
    p.res=x_f; p.ldr=512;
    p.C=cat_bf; p.ldc=1024; p.K=512;
    mma_nt_kernel<64><<<dim3(4,64,1), B256, 0, stream>>>(p); }

  // 8. q_sa = (msca @ saq_w^T + b) * 512^-0.5
  { MmaNT p{}; p.zdiv=1; p.cBf=1; p.scale=0.04419417382415922f;
    p.A=cat_bf; p.lda=1024; p.W=wsaq; p.ldw=512; p.bias=saq_b;
    p.C=qsa; p.ldc=512; p.K=512;
    mma_nt_kernel<64><<<dim3(4,64,1), B256, 0, stream>>>(p); }

  // 9. kv = scene @ sakv_w^T + b   [32768,1024]
  { MmaNT p{}; p.scale=1.f; p.zdiv=1; p.cBf=1;
    p.A=scene_bf; p.lda=512; p.W=wskv; p.ldw=512; p.bias=sakv_b;
    p.C=kv_bf; p.ldc=1024; p.K=512;
    mma_nt_kernel<128><<<dim3(8,256,1), B256, 0, stream>>>(p); }

  // 10. SA attention: V^T -> split flash (NS=4, 128-row 8-wave pipelined) -> merge
  { TransP t{}; t.src=kv_bf+512; t.dst=vT; t.sSb=4194304; t.sSh=128;
    t.ld=1024; t.nh=4; t.N=4096; t.D=128;
    transpose_kernel<<<dim3(64,2,32), B256, 0, stream>>>(t); }
  { FlashP2 p{};
    p.Q=qsa;   p.ldq=128;  p.sQb=262144;  p.sQh=65536;
    p.K=kv_bf; p.ldk=1024; p.sKb=4194304; p.sKh=128;
    p.VT=vT; p.sVz=524288;
    p.prior=prior; p.sPb=2097152;
    p.partO=saO; p.partML=saML;
    p.nh=4; p.N=4096; p.segN=1024; p.scale=1.f;
    flash3_kernel<128,1><<<dim3(4,4,32), B512, 0, stream>>>(p); }
  { MergeP m{}; m.partO=saO; m.partML=saML; m.C=sm_bf;
    m.ldc=512; m.sCb=262144; m.nh=4; m.y=4;
    fmerge_kernel<128,4><<<128, B256, 0, stream>>>(m); }

  // 11. smf = sm @ saout_w^T + b  -> cat[:, 512:1024]
  { MmaNT p{}; p.scale=1.f; p.zdiv=1; p.cBf=1;
    p.A=sm_bf; p.lda=512; p.W=wsout; p.ldw=512; p.bias=saout_b;
    p.C=cat_bf + 512; p.ldc=1024; p.K=512;
    mma_nt_kernel<64><<<dim3(4,64,1), B256, 0, stream>>>(p); }

  // 12. fc1g = gelu(cat @ fc1_w^T + b)   [4096,2048]
  { MmaNT p{}; p.scale=1.f; p.zdiv=1; p.cBf=1; p.act=1;
    p.A=cat_bf; p.lda=1024; p.W=wfc1; p.ldw=1024; p.bias=fc1_b;
    p.C=fc1g; p.ldc=2048; p.K=1024;
    mma_nt_kernel<128><<<dim3(16,32,1), B256, 0, stream>>>(p); }

  // 13. out = fc1g @ fc2_w^T + b  -> d_out fp32
  { MmaNT p{}; p.scale=1.f; p.zdiv=1;
    p.A=fc1g; p.lda=2048; p.W=wfc2; p.ldw=2048; p.bias=fc2_b;
    p.C=d_out; p.ldc=512; p.K=2048;
    mma_nt_kernel<64><<<dim3(4,64,1), B256, 0, stream>>>(p); }
}